// Round 1
// 553.850 us; speedup vs baseline: 2.8124x; 2.8124x over previous
//
#include <hip/hip_runtime.h>

// B=8, S=1024, MD=1024, H=16, D=64. SCALE = (64//16)^-0.5 = 0.5.
// Inputs fp32, OUTPUTS fp32. Internal pipeline bf16 MFMA, fp32 accumulate.
// torch .view(B*H,-1,D) = flat row-major reinterpretation: attention over
// [G=128][T=1024][D=64] with flat pointer math. Crucially, the flat
// row-major [8192][1024] GEMM output IS the [g][t][d] layout, so V^T is
// built by a separate coalesced tile-transpose kernel (the old mode-1
// scatter epilogue caused 703 MB/dispatch of partial-line HBM writes).

typedef __attribute__((ext_vector_type(8))) short bf16x8;
typedef __attribute__((ext_vector_type(4))) float f32x4;
typedef __attribute__((ext_vector_type(4))) int int4v;

static __device__ __forceinline__ short f2bf(float f) {
  union { float f; unsigned u; } v; v.f = f;
  unsigned lsb = (v.u >> 16) & 1u;
  v.u += 0x7fffu + lsb;
  return (short)(v.u >> 16);
}

// async global->LDS, 16B per lane; LDS dest = wave-uniform base + lane*16
#define GLDS16(gp, lp) __builtin_amdgcn_global_load_lds( \
    (const __attribute__((address_space(1))) void*)(gp), \
    (__attribute__((address_space(3))) void*)(lp), 16, 0, 0)

// ---------- fp32 W[k][n] -> bf16 WT[n][k], 64x64 tiles ----------
__global__ __launch_bounds__(256) void convt_f32(
    const float* __restrict__ src, short* __restrict__ dst)
{
  __shared__ float T[64][65];
  const int tid = threadIdx.x;
  const int c0 = blockIdx.x * 64, r0 = blockIdx.y * 64;
  {
    const int rr = tid >> 4, cc = (tid & 15) * 4;
    for (int i = 0; i < 4; ++i) {
      int row = rr + i * 16;
      const float4 v = *(const float4*)(src + (size_t)(r0 + row) * 1024 + c0 + cc);
      T[row][cc] = v.x; T[row][cc + 1] = v.y; T[row][cc + 2] = v.z; T[row][cc + 3] = v.w;
    }
  }
  __syncthreads();
  {
    const int rr = tid >> 3, cc = (tid & 7) * 8;
    for (int i = 0; i < 2; ++i) {
      int row = rr + i * 32;             // dst row within tile (= src col)
      bf16x8 v;
      for (int j = 0; j < 8; ++j) v[j] = f2bf(T[cc + j][row]);
      *(bf16x8*)(dst + (size_t)(c0 + row) * 1024 + r0 + cc) = v;
    }
  }
}

// ---------- fp32 -> bf16 elementwise (A-operand pre-conversion) ----------
// grid * 256 * 8 == n exactly (n = 8M), no bounds check needed.
__global__ __launch_bounds__(256) void cvt_bf16(
    const float* __restrict__ src, short* __restrict__ dst)
{
  const size_t i = ((size_t)blockIdx.x * 256 + threadIdx.x) * 8;
  const float4 v0 = *(const float4*)(src + i);
  const float4 v1 = *(const float4*)(src + i + 4);
  bf16x8 o;
  o[0] = f2bf(v0.x); o[1] = f2bf(v0.y); o[2] = f2bf(v0.z); o[3] = f2bf(v0.w);
  o[4] = f2bf(v1.x); o[5] = f2bf(v1.y); o[6] = f2bf(v1.z); o[7] = f2bf(v1.w);
  *(bf16x8*)(dst + i) = o;
}

// ---------- per-g 64x64 bf16 tile transpose: V[g][t][d] -> VpT[g][d][t] ----
__global__ __launch_bounds__(256) void transp_v(
    const short* __restrict__ src, short* __restrict__ dst)
{
  __shared__ short T[64][72];
  const int g = blockIdx.y, t0 = blockIdx.x * 64;
  const short* s = src + (size_t)g * 65536 + (size_t)t0 * 64;
  short* d = dst + (size_t)g * 65536 + t0;
  const int r = threadIdx.x >> 3, c = (threadIdx.x & 7) * 8;
  for (int i = 0; i < 2; ++i) {
    bf16x8 v = *(const bf16x8*)(s + (size_t)(r + i * 32) * 64 + c);
    *(bf16x8*)(&T[r + i * 32][c]) = v;
  }
  __syncthreads();
  for (int i = 0; i < 2; ++i) {
    int dr = r + i * 32;                 // d index
    bf16x8 v;
    for (int j = 0; j < 8; ++j) v[j] = T[c + j][dr];
    *(bf16x8*)(d + (size_t)dr * 1024 + c) = v;
  }
}

// ---------- GEMM: C[M,N] = A[M,K](bf16) * BT[N,K]^T + bias_f32[N] ----------
// m97 structure: 128x128 tile, BK=64, global_load_lds width-16 staging into
// linear (unpadded -- required by global_load_lds) LDS, 4 waves 2x2.
// mode: 0 = bf16 store C[row*N+col]; 2 = fp32 store (final output).
__global__ __launch_bounds__(256) void gemm_bt16(
    const short* __restrict__ A, const short* __restrict__ BT,
    const float* __restrict__ bias, void* __restrict__ Cp,
    int mode, int M, int N, int K)
{
  __shared__ short As[128 * 64];
  __shared__ short Bs[128 * 64];
  const int tid = threadIdx.x;
  const int lane = tid & 63, wave = tid >> 6;
  const int quad = lane >> 4, l16 = lane & 15;
  const int wm = (wave & 1) * 64, wn = (wave >> 1) * 64;
  const int bm = blockIdx.x * 128, bn = blockIdx.y * 128;

  f32x4 acc[4][4] = {};

  const int s_row = tid >> 3;            // 0..31 (row within 32-row round)
  const int s_col = (tid & 7) * 8;       // 0..56 (shorts)
  const int lds_base = wave * 512;       // wave-uniform (shorts)

  for (int k0 = 0; k0 < K; k0 += 64) {
    for (int i = 0; i < 4; ++i) {
      int row = s_row + i * 32;
      GLDS16(A + (size_t)(bm + row) * K + k0 + s_col, &As[i * 2048 + lds_base]);
      GLDS16(BT + (size_t)(bn + row) * K + k0 + s_col, &Bs[i * 2048 + lds_base]);
    }
    __syncthreads();   // compiler emits vmcnt(0) before barrier
    for (int ks = 0; ks < 2; ++ks) {
      bf16x8 af[4], bfr[4];
      for (int mi = 0; mi < 4; ++mi)
        af[mi] = *(const bf16x8*)(&As[(wm + mi * 16 + l16) * 64 + ks * 32 + quad * 8]);
      for (int ni = 0; ni < 4; ++ni)
        bfr[ni] = *(const bf16x8*)(&Bs[(wn + ni * 16 + l16) * 64 + ks * 32 + quad * 8]);
      for (int mi = 0; mi < 4; ++mi)
        for (int ni = 0; ni < 4; ++ni)
          acc[mi][ni] = __builtin_amdgcn_mfma_f32_16x16x32_bf16(af[mi], bfr[ni], acc[mi][ni], 0, 0, 0);
    }
    __syncthreads();
  }

  for (int ni = 0; ni < 4; ++ni) {
    int col = bn + wn + ni * 16 + l16;
    float bv = bias[col];
    for (int mi = 0; mi < 4; ++mi) {
      int row0 = bm + wm + mi * 16 + quad * 4;   // C row = quad*4+reg
      for (int r = 0; r < 4; ++r) {
        int row = row0 + r;
        float fv = acc[mi][ni][r] + bv;
        if (mode == 2) ((float*)Cp)[(size_t)row * N + col] = fv;
        else           ((short*)Cp)[(size_t)row * N + col] = f2bf(fv);
      }
    }
  }
}

// ---------- fused attention over [G=128,T=1024,D=64] ----------
// block = (b, 16-row t-tile); 4 waves split s into 256-wide strips; 16 heads serial.
// No max-subtraction: scores ~N(0,16), |x|<~35 => exp safe in fp32.
__global__ __launch_bounds__(256) void attn_fused(
    const short* __restrict__ Qp, const short* __restrict__ Kp,
    const short* __restrict__ VpT,               // [g][d][t]
    short* __restrict__ ctx,                     // [g][t][d] flat (bf16)
    float* __restrict__ attn_post)               // [b][t][s] FP32 OUTPUT
{
  __shared__ short Plds[16][1032];
  __shared__ float red[16][4];
  __shared__ float ctxred[4][16][64];

  const int tid = threadIdx.x;
  const int wave = tid >> 6, lane = tid & 63;
  const int quad = lane >> 4, l16 = lane & 15;
  const int b = blockIdx.x >> 6;
  const int t0 = (blockIdx.x & 63) * 16;
  const int sbase = wave * 256;

  float sig[16][4] = {};                         // sigmoid acc over heads

  for (int h = 0; h < 16; ++h) {
    const int g = b * 16 + h;
    const short* Qg = Qp + (size_t)g * 65536;
    const short* Kg = Kp + (size_t)g * 65536;
    const short* Vg = VpT + (size_t)g * 65536;

    bf16x8 aq0 = *(const bf16x8*)(Qg + (t0 + l16) * 64 + quad * 8);
    bf16x8 aq1 = *(const bf16x8*)(Qg + (t0 + l16) * 64 + 32 + quad * 8);

    float sc[16][4];                             // holds e^x
    float rsum[4] = {0.f, 0.f, 0.f, 0.f};
    for (int tile = 0; tile < 16; ++tile) {
      int s = sbase + tile * 16;
      bf16x8 bk0 = *(const bf16x8*)(Kg + (s + l16) * 64 + quad * 8);
      bf16x8 bk1 = *(const bf16x8*)(Kg + (s + l16) * 64 + 32 + quad * 8);
      f32x4 c = {0.f, 0.f, 0.f, 0.f};
      c = __builtin_amdgcn_mfma_f32_16x16x32_bf16(aq0, bk0, c, 0, 0, 0);
      c = __builtin_amdgcn_mfma_f32_16x16x32_bf16(aq1, bk1, c, 0, 0, 0);
      for (int r = 0; r < 4; ++r) {
        float x = c[r] * 0.5f;                   // SCALE = 0.5
        float e = __expf(x);
        sc[tile][r] = e;
        rsum[r] += e;
        sig[tile][r] += e * __builtin_amdgcn_rcpf(1.f + e);   // sigmoid(x)
      }
    }
    for (int r = 0; r < 4; ++r)
      for (int mask = 1; mask < 16; mask <<= 1) rsum[r] += __shfl_xor(rsum[r], mask, 64);
    if (l16 == 0)
      for (int r = 0; r < 4; ++r) red[quad * 4 + r][wave] = rsum[r];
    __syncthreads();                             // B1
    for (int r = 0; r < 4; ++r) {
      int row = quad * 4 + r;
      float s4 = red[row][0] + red[row][1] + red[row][2] + red[row][3];
      float inv = __builtin_amdgcn_rcpf(s4);
      for (int tile = 0; tile < 16; ++tile)
        Plds[row][sbase + tile * 16 + l16] = f2bf(sc[tile][r] * inv);
    }
    f32x4 cacc[4] = {};
    for (int ks = 0; ks < 8; ++ks) {
      bf16x8 ap = *(const bf16x8*)(&Plds[l16][sbase + ks * 32 + quad * 8]);
      for (int ni = 0; ni < 4; ++ni) {
        bf16x8 bv = *(const bf16x8*)(Vg + (ni * 16 + l16) * 1024 + sbase + ks * 32 + quad * 8);
        cacc[ni] = __builtin_amdgcn_mfma_f32_16x16x32_bf16(ap, bv, cacc[ni], 0, 0, 0);
      }
    }
    for (int ni = 0; ni < 4; ++ni)
      for (int r = 0; r < 4; ++r)
        ctxred[wave][quad * 4 + r][ni * 16 + l16] = cacc[ni][r];
    __syncthreads();                             // B2
    short* ctxg = ctx + (size_t)g * 65536 + t0 * 64;
    for (int e = tid; e < 1024; e += 256) {
      int t = e >> 6, dd = e & 63;
      float v = ctxred[0][t][dd] + ctxred[1][t][dd] + ctxred[2][t][dd] + ctxred[3][t][dd];
      ctxg[t * 64 + dd] = f2bf(v);
    }
    // red/Plds/ctxred for head h+1 are written only after h+1's B1 -> safe.
  }

  float* ap_out = attn_post + (size_t)b * 1048576 + (size_t)t0 * 1024;
  for (int tile = 0; tile < 16; ++tile)
    for (int r = 0; r < 4; ++r)
      ap_out[(quad * 4 + r) * 1024 + sbase + tile * 16 + l16] = sig[tile][r] * 0.0625f;
}

extern "C" void kernel_launch(void* const* d_in, const int* in_sizes, int n_in,
                              void* d_out, int out_size, void* d_ws, size_t ws_size,
                              hipStream_t stream) {
  const float* query = (const float*)d_in[0];
  const float* key   = (const float*)d_in[1];
  const float* value = (const float*)d_in[2];
  const float* Wq = (const float*)d_in[3]; const float* bq = (const float*)d_in[4];
  const float* Wk = (const float*)d_in[5]; const float* bk = (const float*)d_in[6];
  const float* Wv = (const float*)d_in[7]; const float* bv = (const float*)d_in[8];
  const float* Wo = (const float*)d_in[9]; const float* bo = (const float*)d_in[10];

  // ws layout (bf16 elements):
  //   WqT,WkT,WvT,WoT : 4 x 1M
  //   Qp, Kp, VpT     : 3 x 8M
  //   Xin             : 8M   (bf16 A-input, reused for Q,K,V; later ctx)
  //   Vflat           : 8M   (V in [g][t][d] before transpose)
  // total 44M shorts = 88 MB
  short* WqT   = (short*)d_ws;
  short* WkT   = WqT + (1u << 20);
  short* WvT   = WkT + (1u << 20);
  short* WoT   = WvT + (1u << 20);
  short* Qp    = WoT + (1u << 20);
  short* Kp    = Qp + (8u << 20);
  short* VpT   = Kp + (8u << 20);
  short* Xin   = VpT + (8u << 20);
  short* Vflat = Xin + (8u << 20);
  short* ctx   = Xin;                       // Xin dead after value-GEMM

  float* out0 = (float*)d_out;              // [8,1024,1024] fp32
  float* attn_post = out0 + (8u << 20);     // [8,1024,1024] fp32

  dim3 blk(256);
  dim3 ggrid(64, 8);
  convt_f32<<<dim3(16, 16), blk, 0, stream>>>(Wq, WqT);
  convt_f32<<<dim3(16, 16), blk, 0, stream>>>(Wk, WkT);
  convt_f32<<<dim3(16, 16), blk, 0, stream>>>(Wv, WvT);
  convt_f32<<<dim3(16, 16), blk, 0, stream>>>(Wo, WoT);

  cvt_bf16<<<dim3(4096), blk, 0, stream>>>(query, Xin);
  gemm_bt16<<<ggrid, blk, 0, stream>>>(Xin, WqT, bq, Qp, 0, 8192, 1024, 1024);
  cvt_bf16<<<dim3(4096), blk, 0, stream>>>(key, Xin);
  gemm_bt16<<<ggrid, blk, 0, stream>>>(Xin, WkT, bk, Kp, 0, 8192, 1024, 1024);
  cvt_bf16<<<dim3(4096), blk, 0, stream>>>(value, Xin);
  gemm_bt16<<<ggrid, blk, 0, stream>>>(Xin, WvT, bv, Vflat, 0, 8192, 1024, 1024);
  transp_v<<<dim3(16, 128), blk, 0, stream>>>(Vflat, VpT);

  attn_fused<<<dim3(512), blk, 0, stream>>>(Qp, Kp, VpT, ctx, attn_post);
  gemm_bt16<<<ggrid, blk, 0, stream>>>(ctx, WoT, bo, out0, 2, 8192, 1024, 1024);
}